// Round 18
// baseline (61.093 us; speedup 1.0000x reference)
//
#include <hip/hip_runtime.h>
#include <hip/hip_bf16.h>
#include <stdint.h>

#define N_ROWS 16384
#define O_ROWS 1024
#define K_DIM  512

typedef __bf16 bf16x8 __attribute__((ext_vector_type(8)));
typedef float  f32x4  __attribute__((ext_vector_type(4)));

__device__ __forceinline__ ushort f2bfu(float f) {
    __bf16 h = (__bf16)f;
    return __builtin_bit_cast(ushort, h);
}

#define BAR_LGKM()  do {                                        \
    asm volatile("s_waitcnt lgkmcnt(0)" ::: "memory");          \
    __builtin_amdgcn_s_barrier();                               \
} while (0)

// ---------------------------------------------------------------------------
// Round 18: A DIRECT-FROM-GLOBAL into MFMA fragments (no A-LDS).
// r12-r17 showed the cost is barrier-fenced phase serialization, not load
// latency. A-frag (row=base+cl, k=ks*32+hi*8, 8 contiguous) is loaded as
// 2x dwordx4 f32 + in-register cvt -> A staging phase disappears; sumsq/cvt
// VALU overlaps MFMA on the separate VALU pipe; LDS traffic drops ~2/3.
//  - BM=256 x BN=128, 256 thr, 4 waves of 64x128 (unique rows/wave -> A read
//    once per block). acc 4x8 frags = 128 AGPR.
//  - B (mean) staged in LDS (1/2 row/thread, T2 XOR swizzle), 16 KB.
//  - bijective XCD swizzle (512 blocks); extended-K-tile epilogue (d2 fully
//    in MFMA acc); #pragma unroll 1 on kt.
// ---------------------------------------------------------------------------
__global__ __launch_bounds__(256, 2) void quadra_kernel(
    const float* __restrict__ x, const float* __restrict__ mean,
    float* __restrict__ out)
{
    __shared__ ushort lds[12288];          // 24 KiB
    ushort* sB  = lds;                     // [128][64] bf16 (swizzled), 16 KiB
    ushort* sAe = lds;                     // alias: [256][32] after main loop
    ushort* sBe = lds + 8192;              // [128][32], 8 KiB

    const int bid  = blockIdx.x;                // 0..511
    const int t    = (bid & 7) * 64 + (bid >> 3);
    const int brow = (t >> 3) * 256;
    const int bcol = (t & 7) * 128;

    const int tid  = threadIdx.x;
    const int lane = tid & 63;
    const int wid  = tid >> 6;                  // 0..3: wave-tile 64x128
    const int cl   = lane & 15, hi = lane >> 4;

    f32x4 acc[4][8] = {};

    // B staging: row = tid>>1 (0..127), h = tid&1 covers k in [h*32, h*32+32)
    const int srow = tid >> 1;
    const int h    = tid & 1;
    const float* gB = mean + (size_t)(bcol + srow) * K_DIM + h * 32;

    // A direct: lane handles rows wid*64 + m*16 + cl, k = kt*64 + ks*32 + hi*8
    const float* gA = x + (size_t)(brow + wid * 64 + cl) * K_DIM + hi * 8;

    float asq[4] = {0.f, 0.f, 0.f, 0.f};
    float bsq = 0.f;

    #pragma unroll 1
    for (int kt = 0; kt < 8; ++kt) {
        // --- stage B only: 32 floats/thread -> bf16(-2m) -> LDS ---
        #pragma unroll
        for (int c = 0; c < 2; ++c) {
            const float* p = gB + kt * 64 + c * 16;
            f32x4 v0 = *(const f32x4*)(p);
            f32x4 v1 = *(const f32x4*)(p + 4);
            f32x4 v2 = *(const f32x4*)(p + 8);
            f32x4 v3 = *(const f32x4*)(p + 12);

            bsq += v0[0]*v0[0] + v0[1]*v0[1] + v0[2]*v0[2] + v0[3]*v0[3]
                 + v1[0]*v1[0] + v1[1]*v1[1] + v1[2]*v1[2] + v1[3]*v1[3]
                 + v2[0]*v2[0] + v2[1]*v2[1] + v2[2]*v2[2] + v2[3]*v2[3]
                 + v3[0]*v3[0] + v3[1]*v3[1] + v3[2]*v3[2] + v3[3]*v3[3];

            bf16x8 c0, c1;
            c0[0] = (__bf16)(v0[0] * -2.0f); c0[1] = (__bf16)(v0[1] * -2.0f);
            c0[2] = (__bf16)(v0[2] * -2.0f); c0[3] = (__bf16)(v0[3] * -2.0f);
            c0[4] = (__bf16)(v1[0] * -2.0f); c0[5] = (__bf16)(v1[1] * -2.0f);
            c0[6] = (__bf16)(v1[2] * -2.0f); c0[7] = (__bf16)(v1[3] * -2.0f);
            c1[0] = (__bf16)(v2[0] * -2.0f); c1[1] = (__bf16)(v2[1] * -2.0f);
            c1[2] = (__bf16)(v2[2] * -2.0f); c1[3] = (__bf16)(v2[3] * -2.0f);
            c1[4] = (__bf16)(v3[0] * -2.0f); c1[5] = (__bf16)(v3[1] * -2.0f);
            c1[6] = (__bf16)(v3[2] * -2.0f); c1[7] = (__bf16)(v3[3] * -2.0f);

            const int b0  = h * 64 + c * 32;               // byte off in row
            const int swz = (srow & 7) << 4;
            *(bf16x8*)(sB + srow * 64 + (((b0)      ^ swz) >> 1)) = c0;
            *(bf16x8*)(sB + srow * 64 + (((b0 + 16) ^ swz) >> 1)) = c1;
        }

        BAR_LGKM();   // B visible

        // --- MFMA phase: A loaded direct from global, cvt in-register ---
        #pragma unroll
        for (int ks = 0; ks < 2; ++ks) {
            bf16x8 a[4];
            #pragma unroll
            for (int m = 0; m < 4; ++m) {
                const float* p = gA + (size_t)(m * 16) * K_DIM + kt * 64 + ks * 32;
                f32x4 v0 = *(const f32x4*)(p);
                f32x4 v1 = *(const f32x4*)(p + 4);
                asq[m] += v0[0]*v0[0] + v0[1]*v0[1] + v0[2]*v0[2] + v0[3]*v0[3]
                        + v1[0]*v1[0] + v1[1]*v1[1] + v1[2]*v1[2] + v1[3]*v1[3];
                bf16x8 cv;
                cv[0] = (__bf16)v0[0]; cv[1] = (__bf16)v0[1];
                cv[2] = (__bf16)v0[2]; cv[3] = (__bf16)v0[3];
                cv[4] = (__bf16)v1[0]; cv[5] = (__bf16)v1[1];
                cv[6] = (__bf16)v1[2]; cv[7] = (__bf16)v1[3];
                a[m] = cv;
            }
            bf16x8 b[8];
            #pragma unroll
            for (int n = 0; n < 8; ++n) {
                const int row = n * 16 + cl;
                const int rb  = (ks * 64 + hi * 16) ^ ((row & 7) << 4);
                b[n] = *(const bf16x8*)(sB + row * 64 + (rb >> 1));
            }
            #pragma unroll
            for (int m = 0; m < 4; ++m)
                #pragma unroll
                for (int n = 0; n < 8; ++n)
                    acc[m][n] = __builtin_amdgcn_mfma_f32_16x16x32_bf16(
                        a[m], b[n], acc[m][n], 0, 0, 0);
        }

        BAR_LGKM();   // B reads drained; next kt may overwrite
    }

    // Extended K-tile: sAe[row(256)] = [xsq,1,0..], sBe[row(128)] = [1,msq,0..]
    // sAe aliases sB (dead after final BAR above).
    #pragma unroll
    for (int m = 0; m < 4; ++m) {
        float sa = asq[m];
        sa += __shfl_xor(sa, 16);
        sa += __shfl_xor(sa, 32);           // all 4 hi-lanes now hold row sum
        const int row = wid * 64 + m * 16 + cl;
        uint4 w = {0u, 0u, 0u, 0u};
        if (hi == 0) w.x = (uint32_t)f2bfu(sa) | (0x3F80u << 16);  // [xsq, 1.0]
        *(uint4*)(sAe + row * 32 + hi * 8) = w;
    }
    {
        float sb = bsq;
        sb += __shfl_xor(sb, 1);            // pair (srow, h=0/1)
        #pragma unroll
        for (int s = 0; s < 2; ++s) {
            uint4 w = {0u, 0u, 0u, 0u};
            if (h == 0 && s == 0)
                w.x = 0x3F80u | ((uint32_t)f2bfu(sb) << 16);       // [1.0, msq]
            *(uint4*)(sBe + srow * 32 + h * 16 + s * 8) = w;
        }
    }
    BAR_LGKM();

    {   // extra MFMA: adds xsq[r] + msq[o] into every accumulator element
        bf16x8 a[4], b[8];
        #pragma unroll
        for (int m = 0; m < 4; ++m)
            a[m] = *(const bf16x8*)(sAe + (wid*64 + m*16 + cl) * 32 + hi * 8);
        #pragma unroll
        for (int n = 0; n < 8; ++n)
            b[n] = *(const bf16x8*)(sBe + (n*16 + cl) * 32 + hi * 8);
        #pragma unroll
        for (int m = 0; m < 4; ++m)
            #pragma unroll
            for (int n = 0; n < 8; ++n)
                acc[m][n] = __builtin_amdgcn_mfma_f32_16x16x32_bf16(
                    a[m], b[n], acc[m][n], 0, 0, 0);
    }

    // epilogue: C/D layout col = lane&15, row = (lane>>4)*4 + j
    const int rg = hi;
    #pragma unroll
    for (int m = 0; m < 4; ++m) {
        #pragma unroll
        for (int j = 0; j < 4; ++j) {
            const int grow = brow + wid*64 + m*16 + rg*4 + j;
            float* orow = out + (size_t)grow * O_ROWS + bcol + cl;
            #pragma unroll
            for (int n = 0; n < 8; ++n)
                orow[n * 16] = rsqrtf(acc[m][n][j]);
        }
    }
}

extern "C" void kernel_launch(void* const* d_in, const int* in_sizes, int n_in,
                              void* d_out, int out_size, void* d_ws, size_t ws_size,
                              hipStream_t stream) {
    const float* x    = (const float*)d_in[0];
    const float* mean = (const float*)d_in[1];
    float* out = (float*)d_out;

    quadra_kernel<<<dim3((N_ROWS / 256) * (O_ROWS / 128)), 256, 0, stream>>>(
        x, mean, out);
}

// Round 20
// 48.665 us; speedup vs baseline: 1.2554x; 1.2554x over previous
//
#include <hip/hip_runtime.h>
#include <hip/hip_bf16.h>
#include <stdint.h>

#define N_ROWS 16384
#define O_ROWS 1024
#define K_DIM  512

typedef __bf16 bf16x8 __attribute__((ext_vector_type(8)));
typedef float  f32x4  __attribute__((ext_vector_type(4)));

__device__ __forceinline__ ushort f2bfu(float f) {
    __bf16 h = (__bf16)f;
    return __builtin_bit_cast(ushort, h);
}

// lgkm-only barrier (proven safe r14-r16): drains LDS ops, leaves global
// loads in flight across the barrier.
#define BAR_LGKM()  do {                                        \
    asm volatile("s_waitcnt lgkmcnt(0)" ::: "memory");          \
    __builtin_amdgcn_s_barrier();                               \
} while (0)

// ---------------------------------------------------------------------------
// Round 20 = round 19 resubmitted verbatim (r19 died to the recurring
// unresponsive MI355X container before the bench could run).
// 256x256 tile (r18's A-direct reverted -- uncoalesced loads + 6x bank
// conflicts). Continues r16's proven lever: per-output work down.
//  - staged rows/out -33% vs r16; LDS frag reads/out -25% (64x128 wave tile);
//    B re-stage redundancy 128x -> 64x.
//  - 512 thr, 8 waves (4M x 2N), acc 4x8 = 128 AGPR. LDS 64 KB single-buf.
//  - grid 256 = 1 block/CU (~2 waves/SIMD at natural VGPR; no min-waves pin).
//  - T2 XOR-swizzle, bijective XCD swizzle (4 col-tiles/panel share L2),
//    extended-K-tile epilogue, lgkm barriers, #pragma unroll 1 on kt.
// ---------------------------------------------------------------------------
__global__ __launch_bounds__(512) void quadra_kernel(
    const float* __restrict__ x, const float* __restrict__ mean,
    float* __restrict__ out)
{
    __shared__ ushort sA[256 * 64];   // [row][k] bf16 (swizzled), 32 KiB
    __shared__ ushort sB[256 * 64];   // [orow][k] bf16 -2*mean (swizzled), 32 KiB

    // XCD swizzle: 256 blocks, XCD c = bid&7 owns tiles t in [c*32, c*32+32);
    // t = panel*4 + col, so the 4 col-tiles of one 256-row x panel stay on
    // one XCD's L2, and mean (2MB) is L2-resident per XCD.
    const int bid  = blockIdx.x;                // 0..255
    const int t    = (bid & 7) * 32 + (bid >> 3);
    const int brow = (t >> 2) * 256;
    const int bcol = (t & 3) * 256;

    const int tid  = threadIdx.x;
    const int lane = tid & 63;
    const int wid  = tid >> 6;                  // 0..7
    const int wm = wid >> 1, wn = wid & 1;      // 4x2 wave grid, 64x128 out each
    const int cl = lane & 15, hi = lane >> 4;

    f32x4 acc[4][8] = {};

    // staging: r0 = tid>>3 (0..63), q = tid&7 (k-octet).
    // thread stages A rows {r0+64i} and B rows {r0+64i}, i=0..3.
    const int r0 = tid >> 3;
    const int q  = tid & 7;

    const float* gA = x    + (size_t)(brow + r0) * K_DIM + q * 8;
    const float* gB = mean + (size_t)(bcol + r0) * K_DIM + q * 8;

    float asq[4] = {0.f, 0.f, 0.f, 0.f};
    float bsq[4] = {0.f, 0.f, 0.f, 0.f};

    #pragma unroll 1
    for (int kt = 0; kt < 8; ++kt) {
        // --- stage A (4 rows/thread) ---
        #pragma unroll
        for (int i = 0; i < 4; ++i) {
            const float* p = gA + (size_t)(i * 64) * K_DIM + kt * 64;
            f32x4 v0 = *(const f32x4*)(p);
            f32x4 v1 = *(const f32x4*)(p + 4);
            asq[i] += v0[0]*v0[0] + v0[1]*v0[1] + v0[2]*v0[2] + v0[3]*v0[3]
                    + v1[0]*v1[0] + v1[1]*v1[1] + v1[2]*v1[2] + v1[3]*v1[3];
            bf16x8 cv;
            cv[0] = (__bf16)v0[0]; cv[1] = (__bf16)v0[1];
            cv[2] = (__bf16)v0[2]; cv[3] = (__bf16)v0[3];
            cv[4] = (__bf16)v1[0]; cv[5] = (__bf16)v1[1];
            cv[6] = (__bf16)v1[2]; cv[7] = (__bf16)v1[3];
            const int row = r0 + i * 64;
            const int wb  = (q * 16) ^ ((row & 7) << 4);
            *(bf16x8*)(sA + row * 64 + (wb >> 1)) = cv;
        }
        // --- stage B (4 rows/thread), scaled by -2 ---
        #pragma unroll
        for (int i = 0; i < 4; ++i) {
            const float* p = gB + (size_t)(i * 64) * K_DIM + kt * 64;
            f32x4 v0 = *(const f32x4*)(p);
            f32x4 v1 = *(const f32x4*)(p + 4);
            bsq[i] += v0[0]*v0[0] + v0[1]*v0[1] + v0[2]*v0[2] + v0[3]*v0[3]
                    + v1[0]*v1[0] + v1[1]*v1[1] + v1[2]*v1[2] + v1[3]*v1[3];
            bf16x8 cv;
            cv[0] = (__bf16)(v0[0] * -2.0f); cv[1] = (__bf16)(v0[1] * -2.0f);
            cv[2] = (__bf16)(v0[2] * -2.0f); cv[3] = (__bf16)(v0[3] * -2.0f);
            cv[4] = (__bf16)(v1[0] * -2.0f); cv[5] = (__bf16)(v1[1] * -2.0f);
            cv[6] = (__bf16)(v1[2] * -2.0f); cv[7] = (__bf16)(v1[3] * -2.0f);
            const int row = r0 + i * 64;
            const int wb  = (q * 16) ^ ((row & 7) << 4);
            *(bf16x8*)(sB + row * 64 + (wb >> 1)) = cv;
        }

        BAR_LGKM();   // staging visible

        #pragma unroll
        for (int ks = 0; ks < 2; ++ks) {
            bf16x8 a[4], b[8];
            #pragma unroll
            for (int m = 0; m < 4; ++m) {
                const int row = wm*64 + m*16 + cl;
                const int rb  = (ks*64 + hi*16) ^ ((row & 7) << 4);
                a[m] = *(const bf16x8*)(sA + row * 64 + (rb >> 1));
            }
            #pragma unroll
            for (int n = 0; n < 8; ++n) {
                const int row = wn*128 + n*16 + cl;
                const int rb  = (ks*64 + hi*16) ^ ((row & 7) << 4);
                b[n] = *(const bf16x8*)(sB + row * 64 + (rb >> 1));
            }
            #pragma unroll
            for (int m = 0; m < 4; ++m)
                #pragma unroll
                for (int n = 0; n < 8; ++n)
                    acc[m][n] = __builtin_amdgcn_mfma_f32_16x16x32_bf16(
                        a[m], b[n], acc[m][n], 0, 0, 0);
        }

        BAR_LGKM();   // reads done; next kt may overwrite
    }

    // Extended K-tile (aliased into sA = 32 KB, dead after the loop):
    //   sAe[row(256)] = [xsq, 1, 0 x30]   sBe[row(256)] = [1, msq, 0 x30]
    ushort* sAe = sA;              // 256*32 = 16 KB
    ushort* sBe = sA + 256 * 32;   // 256*32 = 16 KB
    #pragma unroll
    for (int i = 0; i < 4; ++i) {
        float sa = asq[i], sb = bsq[i];
        #pragma unroll
        for (int msk = 1; msk < 8; msk <<= 1) {
            sa += __shfl_xor(sa, msk);
            sb += __shfl_xor(sb, msk);
        }
        const int row = r0 + i * 64;
        uint2 aw = {0u, 0u}, bw = {0u, 0u};
        if (q == 0) {
            aw.x = (uint32_t)f2bfu(sa) | (0x3F80u << 16);   // [xsq, 1.0]
            bw.x = 0x3F80u | ((uint32_t)f2bfu(sb) << 16);   // [1.0, msq]
        }
        *(uint2*)(sAe + row * 32 + q * 4) = aw;
        *(uint2*)(sBe + row * 32 + q * 4) = bw;
    }
    BAR_LGKM();

    {   // extra MFMA: adds xsq[r] + msq[o] into every accumulator element
        bf16x8 a[4], b[8];
        #pragma unroll
        for (int m = 0; m < 4; ++m)
            a[m] = *(const bf16x8*)(sAe + (wm*64 + m*16 + cl) * 32 + hi * 8);
        #pragma unroll
        for (int n = 0; n < 8; ++n)
            b[n] = *(const bf16x8*)(sBe + (wn*128 + n*16 + cl) * 32 + hi * 8);
        #pragma unroll
        for (int m = 0; m < 4; ++m)
            #pragma unroll
            for (int n = 0; n < 8; ++n)
                acc[m][n] = __builtin_amdgcn_mfma_f32_16x16x32_bf16(
                    a[m], b[n], acc[m][n], 0, 0, 0);
    }

    // epilogue: C/D layout col = lane&15, row = (lane>>4)*4 + j
    #pragma unroll
    for (int m = 0; m < 4; ++m) {
        #pragma unroll
        for (int j = 0; j < 4; ++j) {
            const int grow = brow + wm*64 + m*16 + hi*4 + j;
            float* orow = out + (size_t)grow * O_ROWS + bcol + wn*128 + cl;
            #pragma unroll
            for (int n = 0; n < 8; ++n)
                orow[n * 16] = rsqrtf(acc[m][n][j]);
        }
    }
}

extern "C" void kernel_launch(void* const* d_in, const int* in_sizes, int n_in,
                              void* d_out, int out_size, void* d_ws, size_t ws_size,
                              hipStream_t stream) {
    const float* x    = (const float*)d_in[0];
    const float* mean = (const float*)d_in[1];
    float* out = (float*)d_out;

    quadra_kernel<<<dim3((N_ROWS / 256) * (O_ROWS / 256)), 512, 0, stream>>>(
        x, mean, out);
}

// Round 21
// 44.160 us; speedup vs baseline: 1.3834x; 1.1020x over previous
//
#include <hip/hip_runtime.h>
#include <hip/hip_bf16.h>
#include <stdint.h>

#define N_ROWS 16384
#define O_ROWS 1024
#define K_DIM  512

typedef __bf16 bf16x8 __attribute__((ext_vector_type(8)));
typedef float  f32x4  __attribute__((ext_vector_type(4)));

__device__ __forceinline__ ushort f2bfu(float f) {
    __bf16 h = (__bf16)f;
    return __builtin_bit_cast(ushort, h);
}

#define BAR_LGKM()  do {                                        \
    asm volatile("s_waitcnt lgkmcnt(0)" ::: "memory");          \
    __builtin_amdgcn_s_barrier();                               \
} while (0)

// ---------------------------------------------------------------------------
// Round 21: r16 geometry (256x128, best at 40.6us) + INTRA-KT INTERLEAVE with
// double-buffered LDS, ONE barrier per kt.
// Per kt: {issue loads(kt+1) -> ds_read+MFMA ks0 on buf[cur] ->
//          cvt+sumsq+ds_write(kt+1) into buf[1-cur] -> ds_read+MFMA ks1 -> BAR}
// Loads hide under ks0 MFMA; writes hide under ks1 MFMA; stage phase gone.
// Race-free with 1 bar/kt: reads of buf[p] at kt are lgkm-drained at kt's
// barrier; kt+1 only writes buf[1-cur].
// Tests interleave-vs-occupancy: LDS 96KB -> 1 blk/CU (r20 baseline for
// 1 blk/CU without interleave: 48.7us; r16 2-blk no-interleave: 40.6us).
//  - 512 thr, 8 waves (4x2), 64x64 wave tiles, acc 4x4 = 64 AGPR.
//  - T2 XOR-swizzle, bijective XCD swizzle, extended-K-tile epilogue,
//    #pragma unroll 1 on kt (r10 lesson).
// ---------------------------------------------------------------------------
__global__ __launch_bounds__(512) void quadra_kernel(
    const float* __restrict__ x, const float* __restrict__ mean,
    float* __restrict__ out)
{
    __shared__ ushort sA[2][256 * 64];   // 64 KiB (swizzled)
    __shared__ ushort sB[2][128 * 64];   // 32 KiB (swizzled, -2*mean)

    const int bid  = blockIdx.x;                // 0..511
    const int t    = (bid & 7) * 64 + (bid >> 3);
    const int brow = (t >> 3) * 256;
    const int bcol = (t & 7) * 128;

    const int tid  = threadIdx.x;
    const int lane = tid & 63;
    const int wid  = tid >> 6;                  // 0..7
    const int wr = wid >> 1, wc = wid & 1;      // 4x2 wave grid, 64x64 out each
    const int cl = lane & 15, hi = lane >> 4;

    f32x4 acc[4][4] = {};

    // staging: r0 = tid>>3 (0..63), q = tid&7 (k-octet).
    // thread stages A rows {r0+64i : i=0..3}, B rows {r0+64i : i=0..1}.
    const int r0 = tid >> 3;
    const int q  = tid & 7;

    const float* gA = x    + (size_t)(brow + r0) * K_DIM + q * 8;
    const float* gB = mean + (size_t)(bcol + r0) * K_DIM + q * 8;

    float asq[4] = {0.f, 0.f, 0.f, 0.f};
    float bsq[2] = {0.f, 0.f};

    f32x4 pa[4][2], pb[2][2];

    // ---- prologue: load + stage kt=0 into buf 0 ----
    #pragma unroll
    for (int i = 0; i < 4; ++i) {
        const float* p = gA + (size_t)(i * 64) * K_DIM;
        pa[i][0] = *(const f32x4*)(p);
        pa[i][1] = *(const f32x4*)(p + 4);
    }
    #pragma unroll
    for (int i = 0; i < 2; ++i) {
        const float* p = gB + (size_t)(i * 64) * K_DIM;
        pb[i][0] = *(const f32x4*)(p);
        pb[i][1] = *(const f32x4*)(p + 4);
    }
    #pragma unroll
    for (int i = 0; i < 4; ++i) {
        f32x4 v0 = pa[i][0], v1 = pa[i][1];
        asq[i] += v0[0]*v0[0] + v0[1]*v0[1] + v0[2]*v0[2] + v0[3]*v0[3]
                + v1[0]*v1[0] + v1[1]*v1[1] + v1[2]*v1[2] + v1[3]*v1[3];
        bf16x8 cv;
        cv[0] = (__bf16)v0[0]; cv[1] = (__bf16)v0[1];
        cv[2] = (__bf16)v0[2]; cv[3] = (__bf16)v0[3];
        cv[4] = (__bf16)v1[0]; cv[5] = (__bf16)v1[1];
        cv[6] = (__bf16)v1[2]; cv[7] = (__bf16)v1[3];
        const int row = r0 + i * 64;
        const int wb  = (q * 16) ^ ((row & 7) << 4);
        *(bf16x8*)(&sA[0][0] + row * 64 + (wb >> 1)) = cv;
    }
    #pragma unroll
    for (int i = 0; i < 2; ++i) {
        f32x4 v0 = pb[i][0], v1 = pb[i][1];
        bsq[i] += v0[0]*v0[0] + v0[1]*v0[1] + v0[2]*v0[2] + v0[3]*v0[3]
                + v1[0]*v1[0] + v1[1]*v1[1] + v1[2]*v1[2] + v1[3]*v1[3];
        bf16x8 cv;
        cv[0] = (__bf16)(v0[0] * -2.0f); cv[1] = (__bf16)(v0[1] * -2.0f);
        cv[2] = (__bf16)(v0[2] * -2.0f); cv[3] = (__bf16)(v0[3] * -2.0f);
        cv[4] = (__bf16)(v1[0] * -2.0f); cv[5] = (__bf16)(v1[1] * -2.0f);
        cv[6] = (__bf16)(v1[2] * -2.0f); cv[7] = (__bf16)(v1[3] * -2.0f);
        const int row = r0 + i * 64;
        const int wb  = (q * 16) ^ ((row & 7) << 4);
        *(bf16x8*)(&sB[0][0] + row * 64 + (wb >> 1)) = cv;
    }
    BAR_LGKM();

    #pragma unroll 1
    for (int kt = 0; kt < 8; ++kt) {
        const int cur = kt & 1;
        ushort* bufA = &sA[cur][0];
        ushort* bufB = &sB[cur][0];
        ushort* nxtA = &sA[cur ^ 1][0];
        ushort* nxtB = &sB[cur ^ 1][0];

        // issue loads for kt+1 (fly under ks0 MFMA)
        if (kt < 7) {
            #pragma unroll
            for (int i = 0; i < 4; ++i) {
                const float* p = gA + (size_t)(i * 64) * K_DIM + (kt + 1) * 64;
                pa[i][0] = *(const f32x4*)(p);
                pa[i][1] = *(const f32x4*)(p + 4);
            }
            #pragma unroll
            for (int i = 0; i < 2; ++i) {
                const float* p = gB + (size_t)(i * 64) * K_DIM + (kt + 1) * 64;
                pb[i][0] = *(const f32x4*)(p);
                pb[i][1] = *(const f32x4*)(p + 4);
            }
        }

        // ---- ks = 0: ds_read + 16 MFMA ----
        {
            bf16x8 a[4], b[4];
            #pragma unroll
            for (int m = 0; m < 4; ++m) {
                const int row = wr*64 + m*16 + cl;
                const int rb  = (hi*16) ^ ((row & 7) << 4);
                a[m] = *(const bf16x8*)(bufA + row * 64 + (rb >> 1));
            }
            #pragma unroll
            for (int n = 0; n < 4; ++n) {
                const int row = wc*64 + n*16 + cl;
                const int rb  = (hi*16) ^ ((row & 7) << 4);
                b[n] = *(const bf16x8*)(bufB + row * 64 + (rb >> 1));
            }
            #pragma unroll
            for (int m = 0; m < 4; ++m)
                #pragma unroll
                for (int n = 0; n < 4; ++n)
                    acc[m][n] = __builtin_amdgcn_mfma_f32_16x16x32_bf16(
                        a[m], b[n], acc[m][n], 0, 0, 0);
        }

        // ---- stage kt+1 into the other buffer (hides under ks1 MFMA) ----
        if (kt < 7) {
            #pragma unroll
            for (int i = 0; i < 4; ++i) {
                f32x4 v0 = pa[i][0], v1 = pa[i][1];
                asq[i] += v0[0]*v0[0] + v0[1]*v0[1] + v0[2]*v0[2] + v0[3]*v0[3]
                        + v1[0]*v1[0] + v1[1]*v1[1] + v1[2]*v1[2] + v1[3]*v1[3];
                bf16x8 cv;
                cv[0] = (__bf16)v0[0]; cv[1] = (__bf16)v0[1];
                cv[2] = (__bf16)v0[2]; cv[3] = (__bf16)v0[3];
                cv[4] = (__bf16)v1[0]; cv[5] = (__bf16)v1[1];
                cv[6] = (__bf16)v1[2]; cv[7] = (__bf16)v1[3];
                const int row = r0 + i * 64;
                const int wb  = (q * 16) ^ ((row & 7) << 4);
                *(bf16x8*)(nxtA + row * 64 + (wb >> 1)) = cv;
            }
            #pragma unroll
            for (int i = 0; i < 2; ++i) {
                f32x4 v0 = pb[i][0], v1 = pb[i][1];
                bsq[i] += v0[0]*v0[0] + v0[1]*v0[1] + v0[2]*v0[2] + v0[3]*v0[3]
                        + v1[0]*v1[0] + v1[1]*v1[1] + v1[2]*v1[2] + v1[3]*v1[3];
                bf16x8 cv;
                cv[0] = (__bf16)(v0[0] * -2.0f); cv[1] = (__bf16)(v0[1] * -2.0f);
                cv[2] = (__bf16)(v0[2] * -2.0f); cv[3] = (__bf16)(v0[3] * -2.0f);
                cv[4] = (__bf16)(v1[0] * -2.0f); cv[5] = (__bf16)(v1[1] * -2.0f);
                cv[6] = (__bf16)(v1[2] * -2.0f); cv[7] = (__bf16)(v1[3] * -2.0f);
                const int row = r0 + i * 64;
                const int wb  = (q * 16) ^ ((row & 7) << 4);
                *(bf16x8*)(nxtB + row * 64 + (wb >> 1)) = cv;
            }
        }

        // ---- ks = 1: ds_read + 16 MFMA ----
        {
            bf16x8 a[4], b[4];
            #pragma unroll
            for (int m = 0; m < 4; ++m) {
                const int row = wr*64 + m*16 + cl;
                const int rb  = (64 + hi*16) ^ ((row & 7) << 4);
                a[m] = *(const bf16x8*)(bufA + row * 64 + (rb >> 1));
            }
            #pragma unroll
            for (int n = 0; n < 4; ++n) {
                const int row = wc*64 + n*16 + cl;
                const int rb  = (64 + hi*16) ^ ((row & 7) << 4);
                b[n] = *(const bf16x8*)(bufB + row * 64 + (rb >> 1));
            }
            #pragma unroll
            for (int m = 0; m < 4; ++m)
                #pragma unroll
                for (int n = 0; n < 4; ++n)
                    acc[m][n] = __builtin_amdgcn_mfma_f32_16x16x32_bf16(
                        a[m], b[n], acc[m][n], 0, 0, 0);
        }

        BAR_LGKM();   // my reads of buf[cur] drained; kt+1 may write buf[cur^1]
                      // (already did) and kt+2 may write buf[cur] after its bar
    }

    // Extended K-tile (aliased into sA[0], dead after the loop):
    //   sAe[row(256)] = [xsq, 1, 0 x30]   sBe[row(128)] = [1, msq, 0 x30]
    ushort* sAe = &sA[0][0];              // 16 KB
    ushort* sBe = &sA[0][0] + 256 * 32;   //  8 KB
    #pragma unroll
    for (int i = 0; i < 4; ++i) {
        float sa = asq[i];
        #pragma unroll
        for (int msk = 1; msk < 8; msk <<= 1) sa += __shfl_xor(sa, msk);
        uint2 aw = {0u, 0u};
        if (q == 0) aw.x = (uint32_t)f2bfu(sa) | (0x3F80u << 16);  // [xsq, 1.0]
        *(uint2*)(sAe + (r0 + i * 64) * 32 + q * 4) = aw;
    }
    #pragma unroll
    for (int i = 0; i < 2; ++i) {
        float sb = bsq[i];
        #pragma unroll
        for (int msk = 1; msk < 8; msk <<= 1) sb += __shfl_xor(sb, msk);
        uint2 bw = {0u, 0u};
        if (q == 0) bw.x = 0x3F80u | ((uint32_t)f2bfu(sb) << 16);  // [1.0, msq]
        *(uint2*)(sBe + (r0 + i * 64) * 32 + q * 4) = bw;
    }
    BAR_LGKM();

    {   // extra MFMA: adds xsq[r] + msq[o] into every accumulator element
        bf16x8 a[4], b[4];
        #pragma unroll
        for (int m = 0; m < 4; ++m)
            a[m] = *(const bf16x8*)(sAe + (wr*64 + m*16 + cl) * 32 + hi * 8);
        #pragma unroll
        for (int n = 0; n < 4; ++n)
            b[n] = *(const bf16x8*)(sBe + (wc*64 + n*16 + cl) * 32 + hi * 8);
        #pragma unroll
        for (int m = 0; m < 4; ++m)
            #pragma unroll
            for (int n = 0; n < 4; ++n)
                acc[m][n] = __builtin_amdgcn_mfma_f32_16x16x32_bf16(
                    a[m], b[n], acc[m][n], 0, 0, 0);
    }

    // epilogue: C/D layout col = lane&15, row = (lane>>4)*4 + j
    #pragma unroll
    for (int m = 0; m < 4; ++m) {
        #pragma unroll
        for (int j = 0; j < 4; ++j) {
            const int grow = brow + wr*64 + m*16 + hi*4 + j;
            float* orow = out + (size_t)grow * O_ROWS + bcol + wc*64 + cl;
            #pragma unroll
            for (int n = 0; n < 4; ++n)
                orow[n * 16] = rsqrtf(acc[m][n][j]);
        }
    }
}

extern "C" void kernel_launch(void* const* d_in, const int* in_sizes, int n_in,
                              void* d_out, int out_size, void* d_ws, size_t ws_size,
                              hipStream_t stream) {
    const float* x    = (const float*)d_in[0];
    const float* mean = (const float*)d_in[1];
    float* out = (float*)d_out;

    quadra_kernel<<<dim3((N_ROWS / 256) * (O_ROWS / 128)), 512, 0, stream>>>(
        x, mean, out);
}